// Round 1
// baseline (5810.968 us; speedup 1.0000x reference)
//
#include <hip/hip_runtime.h>

// LSTM last-h + LeakyReLU(0.3). B=128 T=1024 F=64 H=256.
// R18: register-resident weights + 2-way col split + in-wave gates.
//  - 256 WGs = 128 rows x 2 col-groups (512 gate-cols each). Clique = 2 WGs
//    (bids r, r+128 -> same XCD mod 8). 1 partner instead of R17's 3.
//  - 1024 thr = 512 cols x 2 k-halves. k' = [x 0..63 | own h 64..191 |
//    partner h 192..319]; word w (uint4, 8 k') split by parity: kh = w&1.
//    Per thread 20 words = 80 fdot2/step (same FLOPs as R17) but weights
//    live in 80 VGPRs, loaded ONCE -- kills 147KB/CU/step of LDS weight
//    streaming and its lgkm stalls (R17's biggest non-VALU cost).
//  - col c = j*4 + g puts the 4 gates of h-col j in ONE wave: gates via
//    3 shfl_down after the kh shfl_xor reduce. No zs[], no B2 barrier.
//  - gather wave (wave 15) polls AFTER its early dots: B1 releases at
//    max(D_early, RTT) instead of R17's RTT + D_early.
//  - 2 barriers/step (B1 partner-visible, B3 xh swap). LDS = 1.3 KB.

#define BATCH   128
#define TSTEPS  1024
#define FDIM    64
#define HDIM    256
#define G4      1024
#define NWORDS  20                               // uint4 words per thread
#define W4S_U4     (2 * NWORDS * 1024)           // 40960 uint4
#define W4S_BYTES  (W4S_U4 * 16)                 // 655360
#define EX_OFF     W4S_BYTES
#define EX_SLOTS   (BATCH * 2 * 2 * 64)          // 32768 uint64 slots
#define EX_BYTES   (EX_SLOTS * 8)                // 262144
#define WS_NEED    (EX_OFF + EX_BYTES)           // 917504 (same as R17)

typedef _Float16 half2_t __attribute__((ext_vector_type(2)));

__device__ __forceinline__ half2_t as_h2(unsigned u) {
    union { unsigned u; half2_t h; } c; c.u = u; return c.h;
}
__device__ __forceinline__ float fdot2f(half2_t a, half2_t b, float c) {
    return __builtin_amdgcn_fdot2(a, b, c, false);
}
__device__ __forceinline__ unsigned pack2(float a, float b) {
    union { _Float16 h[2]; unsigned u; } c;
    c.h[0] = (_Float16)a; c.h[1] = (_Float16)b; return c.u;
}

#define DOT4(a0,a1,a2,a3,xv,wv) \
    a0 = fdot2f(as_h2((xv).x), as_h2((wv).x), a0); \
    a1 = fdot2f(as_h2((xv).y), as_h2((wv).y), a1); \
    a2 = fdot2f(as_h2((xv).z), as_h2((wv).z), a2); \
    a3 = fdot2f(as_h2((xv).w), as_h2((wv).w), a3);

// w4s layout: [cg][wi 0..19][tid 0..1023] uint4 -- coalesced reg-load.
// thread tid: c = tid>>1 (c = j*4+g), kh = tid&1; word w = 2*wi+kh;
// dword d covers k' = 8w+2d, 8w+2d+1.
__global__ void pack_weights2(const float* __restrict__ wk,
                              const float* __restrict__ wr,
                              unsigned* __restrict__ w4s) {
    int idx = blockIdx.x * blockDim.x + threadIdx.x;
    if (idx >= W4S_U4 * 4) return;
    int u4 = idx >> 2, d = idx & 3;
    int tid = u4 & 1023;
    int wi  = (u4 >> 10) % NWORDS;
    int cg  = u4 / (NWORDS * 1024);
    int c = tid >> 1, kh = tid & 1;
    int j = c >> 2, g = c & 3;
    int gcol = g * 256 + cg * 128 + j;
    int w = 2 * wi + kh;
    float v[2];
    #pragma unroll
    for (int s2 = 0; s2 < 2; ++s2) {
        int kp = 8 * w + 2 * d + s2;
        if (kp < 64)       v[s2] = wk[kp * G4 + gcol];
        else if (kp < 192) v[s2] = wr[(cg * 128 + (kp - 64)) * G4 + gcol];
        else               v[s2] = wr[((cg ^ 1) * 128 + (kp - 192)) * G4 + gcol];
    }
    w4s[idx] = pack2(v[0], v[1]);
}

__global__ __launch_bounds__(1024) void lstm_2way(
    const float* __restrict__ inputs,
    const uint4* __restrict__ w4s,
    const float* __restrict__ bias,
    unsigned long long* __restrict__ ex2,
    float* __restrict__ out)
{
    // xh dwords: [0..31] x_t f16-pairs, [32..95] own h, [96..159] partner h
    __shared__ uint4 xh4[2][40];

    const int bid = blockIdx.x;
    const int cg  = bid >> 7;
    const int row = bid & 127;
    const int tid = threadIdx.x;
    const int kh  = tid & 1;
    const int j   = tid >> 3;        // h-col (local) for gate lanes

    // ---- weights -> 80 VGPRs, once ----
    uint4 Wv[NWORDS];
    {
        const uint4* __restrict__ Wp = w4s + (size_t)cg * NWORDS * 1024 + tid;
        #pragma unroll
        for (int wi = 0; wi < NWORDS; ++wi) Wv[wi] = Wp[wi * 1024];
    }

    const float* __restrict__ xrow = inputs + (size_t)row * TSTEPS * FDIM;

    // init xh[0]: x_0 packed, h_0 = 0 (own + partner regions)
    if (tid < 32) {
        float2 x2 = ((const float2*)xrow)[tid];
        ((unsigned*)&xh4[0][0])[tid] = pack2(x2.x, x2.y);
    } else if (tid < 160) {
        ((unsigned*)&xh4[0][0])[tid] = 0u;
    }

    const float bi = bias[        cg * 128 + j];
    const float bf = bias[256   + cg * 128 + j];
    const float bc = bias[512   + cg * 128 + j];
    const float bo = bias[768   + cg * 128 + j];

    unsigned long long* const pubB = ex2 + (size_t)((row * 2 + cg)       * 2) * 64;
    unsigned long long* const polB = ex2 + (size_t)((row * 2 + (cg ^ 1)) * 2) * 64;

    const bool gatherer = (tid >= 960);          // wave 15, lane gl -> slot gl
    const int  gl = tid - 960;
    const bool stager = (tid >= 512 && tid < 544);
    const int  sx = tid - 512;

    float cstate = 0.0f;
    __syncthreads();

    for (int s = 0; s < TSTEPS; ++s) {
        const int cp = s & 1, ncp = cp ^ 1;
        const uint4* __restrict__ Xk = &xh4[cp][0] + kh;   // word w = 2*wi+kh

        // speculative poll issue (flies under early dots)
        unsigned long long* const psrc = polB + (size_t)(s & 1) * 64 + gl;
        unsigned long long pv = 0;
        if (gatherer && s > 0)
            pv = __hip_atomic_load(psrc, __ATOMIC_RELAXED, __HIP_MEMORY_SCOPE_AGENT);

        // x_{s+1} prefetch (vmcnt wait lands after the dots)
        float2 xnext = make_float2(0.f, 0.f);
        if (stager && s + 1 < TSTEPS)
            xnext = ((const float2*)(xrow + (s + 1) * FDIM))[sx];

        float A0 = 0.f, A1 = 0.f, A2 = 0.f, A3 = 0.f;

        // early dots: x + own h (12 words, reg weights, LDS broadcast reads)
        #pragma unroll
        for (int wi = 0; wi < 12; ++wi) {
            uint4 xv = Xk[2 * wi];
            DOT4(A0, A1, A2, A3, xv, Wv[wi]);
        }

        // gather AFTER early dots: B1 releases at max(D_early, RTT)
        if (gatherer && s > 0) {
            int it = 0;
            while ((unsigned)(pv >> 32) != (unsigned)s && ++it < (1 << 22))
                pv = __hip_atomic_load(psrc, __ATOMIC_RELAXED,
                                       __HIP_MEMORY_SCOPE_AGENT);
            unsigned pdw = ((unsigned)(pv >> 32) == (unsigned)s) ? (unsigned)pv : 0u;
            ((unsigned*)&xh4[cp][24])[gl] = pdw;           // dw 96+gl
        }
        __syncthreads();                                   // B1

        // late dots: partner h (8 words)
        #pragma unroll
        for (int wi = 12; wi < 20; ++wi) {
            uint4 xv = Xk[2 * wi];
            DOT4(A0, A1, A2, A3, xv, Wv[wi]);
        }

        // reduce kh halves, then gather the 4 gates in-wave
        float z = (A0 + A1) + (A2 + A3);
        z += __shfl_xor(z, 1);
        const float zfv = __shfl_down(z, 2);
        const float zcv = __shfl_down(z, 4);
        const float zov = __shfl_down(z, 6);

        // gate math (all lanes execute; only tid&7==0 lanes hold real values)
        const float zi = z   + bi;
        const float zf = zfv + bf;
        const float zc = zcv + bc;
        const float zo = zov + bo;
        const float ig = 1.0f / (1.0f + __expf(-zi));
        const float fg = 1.0f / (1.0f + __expf(-zf));
        const float gg = 1.0f - 2.0f / (__expf(2.0f * zc) + 1.0f);
        const float og = 1.0f / (1.0f + __expf(-zo));
        cstate = fmaf(fg, cstate, ig * gg);
        const float hn = og * (1.0f - 2.0f / (__expf(2.0f * cstate) + 1.0f));
        const float hno = __shfl_down(hn, 8);              // h_{j+1}

        if ((tid & 7) == 0) {
            if (s == TSTEPS - 1) {
                const float h = hn;
                out[row * HDIM + cg * 128 + j] = (h >= 0.0f) ? h : 0.3f * h;
            } else if ((tid & 15) == 0) {                  // even j
                const unsigned u = pack2(hn, hno);
                const unsigned long long pvw =
                    ((unsigned long long)(unsigned)(s + 1) << 32) |
                    (unsigned long long)u;
                __hip_atomic_store(pubB + (size_t)((s + 1) & 1) * 64 + (j >> 1),
                                   pvw, __ATOMIC_RELAXED,
                                   __HIP_MEMORY_SCOPE_AGENT);
                ((unsigned*)&xh4[ncp][8])[j >> 1] = u;     // own h, dw 32+j/2
            }
        }
        if (stager && s + 1 < TSTEPS)
            ((unsigned*)&xh4[ncp][0])[sx] = pack2(xnext.x, xnext.y);
        __syncthreads();                                   // B3
    }
}

// ---- fallback (needs no ws): round-1 kernel ----
__global__ __launch_bounds__(HDIM) void lstm_fused(
    const float* __restrict__ inputs, const float* __restrict__ wk,
    const float* __restrict__ wr, const float* __restrict__ bias,
    float* __restrict__ out)
{
    const int b = blockIdx.x;
    const int t = threadIdx.x;
    __shared__ float hs[2][HDIM];
    __shared__ float xs[2][FDIM];
    const float* __restrict__ xin = inputs + (size_t)b * TSTEPS * FDIM;
    float c = 0.0f;
    hs[0][t] = 0.0f;
    if (t < FDIM) xs[0][t] = xin[t];
    const float bi = bias[t];
    const float bf = bias[HDIM + t];
    const float bc = bias[2 * HDIM + t];
    const float bo = bias[3 * HDIM + t];
    __syncthreads();
    int p = 0;
    for (int step = 0; step < TSTEPS; ++step) {
        float zi = bi, zf = bf, zc = bc, zo = bo;
        const float* xsp = xs[p];
        const float* hsp = hs[p];
        #pragma unroll 8
        for (int f = 0; f < FDIM; ++f) {
            const float xv = xsp[f];
            const float* Kf = wk + f * G4 + t;
            zi = fmaf(xv, Kf[0], zi);
            zf = fmaf(xv, Kf[HDIM], zf);
            zc = fmaf(xv, Kf[2 * HDIM], zc);
            zo = fmaf(xv, Kf[3 * HDIM], zo);
        }
        #pragma unroll 8
        for (int k = 0; k < HDIM; ++k) {
            const float hv = hsp[k];
            const float* Rk = wr + k * G4 + t;
            zi = fmaf(hv, Rk[0], zi);
            zf = fmaf(hv, Rk[HDIM], zf);
            zc = fmaf(hv, Rk[2 * HDIM], zc);
            zo = fmaf(hv, Rk[3 * HDIM], zo);
        }
        const float ig = 1.0f / (1.0f + __expf(-zi));
        const float fg = 1.0f / (1.0f + __expf(-zf));
        const float gg = 1.0f - 2.0f / (__expf(2.0f * zc) + 1.0f);
        const float og = 1.0f / (1.0f + __expf(-zo));
        c = fmaf(fg, c, ig * gg);
        const float hn = og * (1.0f - 2.0f / (__expf(2.0f * c) + 1.0f));
        float xnext = 0.0f;
        if (t < FDIM && step + 1 < TSTEPS) xnext = xin[(step + 1) * FDIM + t];
        hs[p ^ 1][t] = hn;
        if (t < FDIM) xs[p ^ 1][t] = xnext;
        __syncthreads();
        p ^= 1;
    }
    const float h = hs[p][t];
    out[b * HDIM + t] = (h >= 0.0f) ? h : 0.3f * h;
}

extern "C" void kernel_launch(void* const* d_in, const int* in_sizes, int n_in,
                              void* d_out, int out_size, void* d_ws, size_t ws_size,
                              hipStream_t stream) {
    const float* inputs = (const float*)d_in[0];
    const float* wk     = (const float*)d_in[1];
    const float* wr     = (const float*)d_in[2];
    const float* bias   = (const float*)d_in[3];
    float* out          = (float*)d_out;

    if (ws_size >= (size_t)WS_NEED) {
        unsigned* w4s = (unsigned*)d_ws;
        unsigned long long* ex2 = (unsigned long long*)((char*)d_ws + EX_OFF);
        hipMemsetAsync(ex2, 0xFF, EX_BYTES, stream);   // all tags invalid
        int ndw = W4S_U4 * 4;
        pack_weights2<<<dim3((ndw + 255) / 256), dim3(256), 0, stream>>>(wk, wr, w4s);
        lstm_2way<<<dim3(256), dim3(1024), 0, stream>>>(
            inputs, (const uint4*)w4s, bias, ex2, out);
    } else {
        lstm_fused<<<dim3(BATCH), dim3(HDIM), 0, stream>>>(inputs, wk, wr, bias, out);
    }
}

// Round 2
// 5787.721 us; speedup vs baseline: 1.0040x; 1.0040x over previous
//
#include <hip/hip_runtime.h>

// LSTM last-h + LeakyReLU(0.3). B=128 T=1024 F=64 H=256.
// R19: R18 + __launch_bounds__(1024, 4).
// R18 post-mortem: with __launch_bounds__(1024) the compiler targeted
// 2 blocks/CU and capped VGPRs at 64, so the 20 uint4 (80 VGPR) weight
// array could NOT be register-resident -> 20 global_load_dwordx4 per
// thread PER STEP (FETCH_SIZE 95MB -> 769MB, VALUBusy 43 -> 25%,
// 1790 -> 5400us). The grid is exactly 256 WGs on 256 CUs, so the
// 2-blocks/CU target was unreachable anyway. Forcing min 4 waves/EU
// (= 1 block/CU) raises the VGPR cap to 128: weights (80) + working
// set (~30) fit, loads happen ONCE.
// Structure (unchanged from R18):
//  - 256 WGs = 128 rows x 2 col-groups (512 gate-cols each); clique = 2
//    WGs (bids r, r+128 -> same XCD mod 8), 1 partner.
//  - 1024 thr = 512 cols x 2 k-halves; k' = [x 0..63 | own h 64..191 |
//    partner h 192..319]; uint4 word w split by parity kh = w&1;
//    20 words = 80 fdot2/thread/step, weights in VGPRs.
//  - col c = j*4+g: 4 gates of h-col j in one wave -> gates via
//    shfl_down, no zs[], no mid barrier.
//  - gather wave (15) polls AFTER its early dots: B1 at max(D_early, RTT).
//  - 2 barriers/step, LDS = 1.3 KB.

#define BATCH   128
#define TSTEPS  1024
#define FDIM    64
#define HDIM    256
#define G4      1024
#define NWORDS  20                               // uint4 words per thread
#define W4S_U4     (2 * NWORDS * 1024)           // 40960 uint4
#define W4S_BYTES  (W4S_U4 * 16)                 // 655360
#define EX_OFF     W4S_BYTES
#define EX_SLOTS   (BATCH * 2 * 2 * 64)          // 32768 uint64 slots
#define EX_BYTES   (EX_SLOTS * 8)                // 262144
#define WS_NEED    (EX_OFF + EX_BYTES)           // 917504 (same as R17)

typedef _Float16 half2_t __attribute__((ext_vector_type(2)));

__device__ __forceinline__ half2_t as_h2(unsigned u) {
    union { unsigned u; half2_t h; } c; c.u = u; return c.h;
}
__device__ __forceinline__ float fdot2f(half2_t a, half2_t b, float c) {
    return __builtin_amdgcn_fdot2(a, b, c, false);
}
__device__ __forceinline__ unsigned pack2(float a, float b) {
    union { _Float16 h[2]; unsigned u; } c;
    c.h[0] = (_Float16)a; c.h[1] = (_Float16)b; return c.u;
}

#define DOT4(a0,a1,a2,a3,xv,wv) \
    a0 = fdot2f(as_h2((xv).x), as_h2((wv).x), a0); \
    a1 = fdot2f(as_h2((xv).y), as_h2((wv).y), a1); \
    a2 = fdot2f(as_h2((xv).z), as_h2((wv).z), a2); \
    a3 = fdot2f(as_h2((xv).w), as_h2((wv).w), a3);

// w4s layout: [cg][wi 0..19][tid 0..1023] uint4 -- coalesced reg-load.
// thread tid: c = tid>>1 (c = j*4+g), kh = tid&1; word w = 2*wi+kh;
// dword d covers k' = 8w+2d, 8w+2d+1.
__global__ void pack_weights2(const float* __restrict__ wk,
                              const float* __restrict__ wr,
                              unsigned* __restrict__ w4s) {
    int idx = blockIdx.x * blockDim.x + threadIdx.x;
    if (idx >= W4S_U4 * 4) return;
    int u4 = idx >> 2, d = idx & 3;
    int tid = u4 & 1023;
    int wi  = (u4 >> 10) % NWORDS;
    int cg  = u4 / (NWORDS * 1024);
    int c = tid >> 1, kh = tid & 1;
    int j = c >> 2, g = c & 3;
    int gcol = g * 256 + cg * 128 + j;
    int w = 2 * wi + kh;
    float v[2];
    #pragma unroll
    for (int s2 = 0; s2 < 2; ++s2) {
        int kp = 8 * w + 2 * d + s2;
        if (kp < 64)       v[s2] = wk[kp * G4 + gcol];
        else if (kp < 192) v[s2] = wr[(cg * 128 + (kp - 64)) * G4 + gcol];
        else               v[s2] = wr[((cg ^ 1) * 128 + (kp - 192)) * G4 + gcol];
    }
    w4s[idx] = pack2(v[0], v[1]);
}

__global__ __launch_bounds__(1024, 4) void lstm_2way(
    const float* __restrict__ inputs,
    const uint4* __restrict__ w4s,
    const float* __restrict__ bias,
    unsigned long long* __restrict__ ex2,
    float* __restrict__ out)
{
    // xh dwords: [0..31] x_t f16-pairs, [32..95] own h, [96..159] partner h
    __shared__ uint4 xh4[2][40];

    const int bid = blockIdx.x;
    const int cg  = bid >> 7;
    const int row = bid & 127;
    const int tid = threadIdx.x;
    const int kh  = tid & 1;
    const int j   = tid >> 3;        // h-col (local) for gate lanes

    // ---- weights -> 80 VGPRs, once ----
    uint4 Wv[NWORDS];
    {
        const uint4* __restrict__ Wp = w4s + (size_t)cg * NWORDS * 1024 + tid;
        #pragma unroll
        for (int wi = 0; wi < NWORDS; ++wi) Wv[wi] = Wp[wi * 1024];
    }

    const float* __restrict__ xrow = inputs + (size_t)row * TSTEPS * FDIM;

    // init xh[0]: x_0 packed, h_0 = 0 (own + partner regions)
    if (tid < 32) {
        float2 x2 = ((const float2*)xrow)[tid];
        ((unsigned*)&xh4[0][0])[tid] = pack2(x2.x, x2.y);
    } else if (tid < 160) {
        ((unsigned*)&xh4[0][0])[tid] = 0u;
    }

    const float bi = bias[        cg * 128 + j];
    const float bf = bias[256   + cg * 128 + j];
    const float bc = bias[512   + cg * 128 + j];
    const float bo = bias[768   + cg * 128 + j];

    unsigned long long* const pubB = ex2 + (size_t)((row * 2 + cg)       * 2) * 64;
    unsigned long long* const polB = ex2 + (size_t)((row * 2 + (cg ^ 1)) * 2) * 64;

    const bool gatherer = (tid >= 960);          // wave 15, lane gl -> slot gl
    const int  gl = tid - 960;
    const bool stager = (tid >= 512 && tid < 544);
    const int  sx = tid - 512;

    float cstate = 0.0f;
    __syncthreads();

    for (int s = 0; s < TSTEPS; ++s) {
        const int cp = s & 1, ncp = cp ^ 1;
        const uint4* __restrict__ Xk = &xh4[cp][0] + kh;   // word w = 2*wi+kh

        // speculative poll issue (flies under early dots)
        unsigned long long* const psrc = polB + (size_t)(s & 1) * 64 + gl;
        unsigned long long pv = 0;
        if (gatherer && s > 0)
            pv = __hip_atomic_load(psrc, __ATOMIC_RELAXED, __HIP_MEMORY_SCOPE_AGENT);

        // x_{s+1} prefetch (vmcnt wait lands after the dots)
        float2 xnext = make_float2(0.f, 0.f);
        if (stager && s + 1 < TSTEPS)
            xnext = ((const float2*)(xrow + (s + 1) * FDIM))[sx];

        float A0 = 0.f, A1 = 0.f, A2 = 0.f, A3 = 0.f;

        // early dots: x + own h (12 words, reg weights, LDS broadcast reads)
        #pragma unroll
        for (int wi = 0; wi < 12; ++wi) {
            uint4 xv = Xk[2 * wi];
            DOT4(A0, A1, A2, A3, xv, Wv[wi]);
        }

        // gather AFTER early dots: B1 releases at max(D_early, RTT)
        if (gatherer && s > 0) {
            int it = 0;
            while ((unsigned)(pv >> 32) != (unsigned)s && ++it < (1 << 22))
                pv = __hip_atomic_load(psrc, __ATOMIC_RELAXED,
                                       __HIP_MEMORY_SCOPE_AGENT);
            unsigned pdw = ((unsigned)(pv >> 32) == (unsigned)s) ? (unsigned)pv : 0u;
            ((unsigned*)&xh4[cp][24])[gl] = pdw;           // dw 96+gl
        }
        __syncthreads();                                   // B1

        // late dots: partner h (8 words)
        #pragma unroll
        for (int wi = 12; wi < 20; ++wi) {
            uint4 xv = Xk[2 * wi];
            DOT4(A0, A1, A2, A3, xv, Wv[wi]);
        }

        // reduce kh halves, then gather the 4 gates in-wave
        float z = (A0 + A1) + (A2 + A3);
        z += __shfl_xor(z, 1);
        const float zfv = __shfl_down(z, 2);
        const float zcv = __shfl_down(z, 4);
        const float zov = __shfl_down(z, 6);

        // gate math (all lanes execute; only tid&7==0 lanes hold real values)
        const float zi = z   + bi;
        const float zf = zfv + bf;
        const float zc = zcv + bc;
        const float zo = zov + bo;
        const float ig = 1.0f / (1.0f + __expf(-zi));
        const float fg = 1.0f / (1.0f + __expf(-zf));
        const float gg = 1.0f - 2.0f / (__expf(2.0f * zc) + 1.0f);
        const float og = 1.0f / (1.0f + __expf(-zo));
        cstate = fmaf(fg, cstate, ig * gg);
        const float hn = og * (1.0f - 2.0f / (__expf(2.0f * cstate) + 1.0f));
        const float hno = __shfl_down(hn, 8);              // h_{j+1}

        if ((tid & 7) == 0) {
            if (s == TSTEPS - 1) {
                const float h = hn;
                out[row * HDIM + cg * 128 + j] = (h >= 0.0f) ? h : 0.3f * h;
            } else if ((tid & 15) == 0) {                  // even j
                const unsigned u = pack2(hn, hno);
                const unsigned long long pvw =
                    ((unsigned long long)(unsigned)(s + 1) << 32) |
                    (unsigned long long)u;
                __hip_atomic_store(pubB + (size_t)((s + 1) & 1) * 64 + (j >> 1),
                                   pvw, __ATOMIC_RELAXED,
                                   __HIP_MEMORY_SCOPE_AGENT);
                ((unsigned*)&xh4[ncp][8])[j >> 1] = u;     // own h, dw 32+j/2
            }
        }
        if (stager && s + 1 < TSTEPS)
            ((unsigned*)&xh4[ncp][0])[sx] = pack2(xnext.x, xnext.y);
        __syncthreads();                                   // B3
    }
}

// ---- fallback (needs no ws): round-1 kernel ----
__global__ __launch_bounds__(HDIM) void lstm_fused(
    const float* __restrict__ inputs, const float* __restrict__ wk,
    const float* __restrict__ wr, const float* __restrict__ bias,
    float* __restrict__ out)
{
    const int b = blockIdx.x;
    const int t = threadIdx.x;
    __shared__ float hs[2][HDIM];
    __shared__ float xs[2][FDIM];
    const float* __restrict__ xin = inputs + (size_t)b * TSTEPS * FDIM;
    float c = 0.0f;
    hs[0][t] = 0.0f;
    if (t < FDIM) xs[0][t] = xin[t];
    const float bi = bias[t];
    const float bf = bias[HDIM + t];
    const float bc = bias[2 * HDIM + t];
    const float bo = bias[3 * HDIM + t];
    __syncthreads();
    int p = 0;
    for (int step = 0; step < TSTEPS; ++step) {
        float zi = bi, zf = bf, zc = bc, zo = bo;
        const float* xsp = xs[p];
        const float* hsp = hs[p];
        #pragma unroll 8
        for (int f = 0; f < FDIM; ++f) {
            const float xv = xsp[f];
            const float* Kf = wk + f * G4 + t;
            zi = fmaf(xv, Kf[0], zi);
            zf = fmaf(xv, Kf[HDIM], zf);
            zc = fmaf(xv, Kf[2 * HDIM], zc);
            zo = fmaf(xv, Kf[3 * HDIM], zo);
        }
        #pragma unroll 8
        for (int k = 0; k < HDIM; ++k) {
            const float hv = hsp[k];
            const float* Rk = wr + k * G4 + t;
            zi = fmaf(hv, Rk[0], zi);
            zf = fmaf(hv, Rk[HDIM], zf);
            zc = fmaf(hv, Rk[2 * HDIM], zc);
            zo = fmaf(hv, Rk[3 * HDIM], zo);
        }
        const float ig = 1.0f / (1.0f + __expf(-zi));
        const float fg = 1.0f / (1.0f + __expf(-zf));
        const float gg = 1.0f - 2.0f / (__expf(2.0f * zc) + 1.0f);
        const float og = 1.0f / (1.0f + __expf(-zo));
        c = fmaf(fg, c, ig * gg);
        const float hn = og * (1.0f - 2.0f / (__expf(2.0f * c) + 1.0f));
        float xnext = 0.0f;
        if (t < FDIM && step + 1 < TSTEPS) xnext = xin[(step + 1) * FDIM + t];
        hs[p ^ 1][t] = hn;
        if (t < FDIM) xs[p ^ 1][t] = xnext;
        __syncthreads();
        p ^= 1;
    }
    const float h = hs[p][t];
    out[b * HDIM + t] = (h >= 0.0f) ? h : 0.3f * h;
}

extern "C" void kernel_launch(void* const* d_in, const int* in_sizes, int n_in,
                              void* d_out, int out_size, void* d_ws, size_t ws_size,
                              hipStream_t stream) {
    const float* inputs = (const float*)d_in[0];
    const float* wk     = (const float*)d_in[1];
    const float* wr     = (const float*)d_in[2];
    const float* bias   = (const float*)d_in[3];
    float* out          = (float*)d_out;

    if (ws_size >= (size_t)WS_NEED) {
        unsigned* w4s = (unsigned*)d_ws;
        unsigned long long* ex2 = (unsigned long long*)((char*)d_ws + EX_OFF);
        hipMemsetAsync(ex2, 0xFF, EX_BYTES, stream);   // all tags invalid
        int ndw = W4S_U4 * 4;
        pack_weights2<<<dim3((ndw + 255) / 256), dim3(256), 0, stream>>>(wk, wr, w4s);
        lstm_2way<<<dim3(256), dim3(1024), 0, stream>>>(
            inputs, (const uint4*)w4s, bias, ex2, out);
    } else {
        lstm_fused<<<dim3(BATCH), dim3(HDIM), 0, stream>>>(inputs, wk, wr, bias, out);
    }
}

// Round 3
// 5277.423 us; speedup vs baseline: 1.1011x; 1.0967x over previous
//
#include <hip/hip_runtime.h>

// LSTM last-h + LeakyReLU(0.3). B=128 T=1024 F=64 H=256.
// R20: R18 structure + FORCED register-resident weights.
// R19 post-mortem: __launch_bounds__(1024,4) only sets a MINIMUM
// occupancy; the compiler still targeted 8 waves/EU -> 64 VGPRs and
// rematerialized the 20 weight loads into the step loop (FETCH 766MB,
// ~5800 cy/step of L2 weight streaming, dur 5.7ms). Two forcings:
//  (1) amdgpu_waves_per_eu(4,4): pins occupancy target to exactly
//      4 waves/EU -> VGPR budget 128 (weights 80 + working set fits).
//  (2) asm volatile("" : "+v"(Wv[wi])) after each load: non-remat
//      use point, loads cannot be sunk into the loop (failure mode
//      becomes visible scratch spill, not silent reload).
// Structure (unchanged from R18):
//  - 256 WGs = 128 rows x 2 col-groups (512 gate-cols each); clique = 2
//    WGs (bids r, r+128 -> same XCD mod 8), 1 partner.
//  - 1024 thr = 512 cols x 2 k-halves; k' = [x 0..63 | own h 64..191 |
//    partner h 192..319]; uint4 word w split by parity kh = w&1;
//    20 words = 80 fdot2/thread/step, weights in VGPRs.
//  - col c = j*4+g: 4 gates of h-col j in one wave -> gates via
//    shfl_down, no zs[], no mid barrier.
//  - gather wave (15) polls AFTER its early dots: B1 at max(D_early, RTT).
//  - 2 barriers/step, LDS = 1.3 KB.

#define BATCH   128
#define TSTEPS  1024
#define FDIM    64
#define HDIM    256
#define G4      1024
#define NWORDS  20                               // uint4 words per thread
#define W4S_U4     (2 * NWORDS * 1024)           // 40960 uint4
#define W4S_BYTES  (W4S_U4 * 16)                 // 655360
#define EX_OFF     W4S_BYTES
#define EX_SLOTS   (BATCH * 2 * 2 * 64)          // 32768 uint64 slots
#define EX_BYTES   (EX_SLOTS * 8)                // 262144
#define WS_NEED    (EX_OFF + EX_BYTES)           // 917504 (same as R17)

typedef _Float16 half2_t __attribute__((ext_vector_type(2)));
typedef unsigned u32x4 __attribute__((ext_vector_type(4)));

__device__ __forceinline__ half2_t as_h2(unsigned u) {
    union { unsigned u; half2_t h; } c; c.u = u; return c.h;
}
__device__ __forceinline__ float fdot2f(half2_t a, half2_t b, float c) {
    return __builtin_amdgcn_fdot2(a, b, c, false);
}
__device__ __forceinline__ unsigned pack2(float a, float b) {
    union { _Float16 h[2]; unsigned u; } c;
    c.h[0] = (_Float16)a; c.h[1] = (_Float16)b; return c.u;
}

#define DOT4(a0,a1,a2,a3,xv,wv) \
    a0 = fdot2f(as_h2((xv).x), as_h2((wv).x), a0); \
    a1 = fdot2f(as_h2((xv).y), as_h2((wv).y), a1); \
    a2 = fdot2f(as_h2((xv).z), as_h2((wv).z), a2); \
    a3 = fdot2f(as_h2((xv).w), as_h2((wv).w), a3);

// w4s layout: [cg][wi 0..19][tid 0..1023] uint4 -- coalesced reg-load.
// thread tid: c = tid>>1 (c = j*4+g), kh = tid&1; word w = 2*wi+kh;
// dword d covers k' = 8w+2d, 8w+2d+1.
__global__ void pack_weights2(const float* __restrict__ wk,
                              const float* __restrict__ wr,
                              unsigned* __restrict__ w4s) {
    int idx = blockIdx.x * blockDim.x + threadIdx.x;
    if (idx >= W4S_U4 * 4) return;
    int u4 = idx >> 2, d = idx & 3;
    int tid = u4 & 1023;
    int wi  = (u4 >> 10) % NWORDS;
    int cg  = u4 / (NWORDS * 1024);
    int c = tid >> 1, kh = tid & 1;
    int j = c >> 2, g = c & 3;
    int gcol = g * 256 + cg * 128 + j;
    int w = 2 * wi + kh;
    float v[2];
    #pragma unroll
    for (int s2 = 0; s2 < 2; ++s2) {
        int kp = 8 * w + 2 * d + s2;
        if (kp < 64)       v[s2] = wk[kp * G4 + gcol];
        else if (kp < 192) v[s2] = wr[(cg * 128 + (kp - 64)) * G4 + gcol];
        else               v[s2] = wr[((cg ^ 1) * 128 + (kp - 192)) * G4 + gcol];
    }
    w4s[idx] = pack2(v[0], v[1]);
}

__global__ __attribute__((amdgpu_flat_work_group_size(1024, 1024),
                          amdgpu_waves_per_eu(4, 4)))
void lstm_2way(
    const float* __restrict__ inputs,
    const uint4* __restrict__ w4s,
    const float* __restrict__ bias,
    unsigned long long* __restrict__ ex2,
    float* __restrict__ out)
{
    // xh dwords: [0..31] x_t f16-pairs, [32..95] own h, [96..159] partner h
    __shared__ uint4 xh4[2][40];

    const int bid = blockIdx.x;
    const int cg  = bid >> 7;
    const int row = bid & 127;
    const int tid = threadIdx.x;
    const int kh  = tid & 1;
    const int j   = tid >> 3;        // h-col (local) for gate lanes

    // ---- weights -> 80 VGPRs, ONCE; asm use-point prevents re-load ----
    u32x4 Wv[NWORDS];
    {
        const u32x4* __restrict__ Wp =
            (const u32x4*)(w4s + (size_t)cg * NWORDS * 1024 + tid);
        #pragma unroll
        for (int wi = 0; wi < NWORDS; ++wi) {
            Wv[wi] = Wp[wi * 1024];
            asm volatile("" : "+v"(Wv[wi]));
        }
    }

    const float* __restrict__ xrow = inputs + (size_t)row * TSTEPS * FDIM;

    // init xh[0]: x_0 packed, h_0 = 0 (own + partner regions)
    if (tid < 32) {
        float2 x2 = ((const float2*)xrow)[tid];
        ((unsigned*)&xh4[0][0])[tid] = pack2(x2.x, x2.y);
    } else if (tid < 160) {
        ((unsigned*)&xh4[0][0])[tid] = 0u;
    }

    const float bi = bias[        cg * 128 + j];
    const float bf = bias[256   + cg * 128 + j];
    const float bc = bias[512   + cg * 128 + j];
    const float bo = bias[768   + cg * 128 + j];

    unsigned long long* const pubB = ex2 + (size_t)((row * 2 + cg)       * 2) * 64;
    unsigned long long* const polB = ex2 + (size_t)((row * 2 + (cg ^ 1)) * 2) * 64;

    const bool gatherer = (tid >= 960);          // wave 15, lane gl -> slot gl
    const int  gl = tid - 960;
    const bool stager = (tid >= 512 && tid < 544);
    const int  sx = tid - 512;

    float cstate = 0.0f;
    __syncthreads();

    for (int s = 0; s < TSTEPS; ++s) {
        const int cp = s & 1, ncp = cp ^ 1;
        const uint4* __restrict__ Xk = &xh4[cp][0] + kh;   // word w = 2*wi+kh

        // speculative poll issue (flies under early dots)
        unsigned long long* const psrc = polB + (size_t)(s & 1) * 64 + gl;
        unsigned long long pv = 0;
        if (gatherer && s > 0)
            pv = __hip_atomic_load(psrc, __ATOMIC_RELAXED, __HIP_MEMORY_SCOPE_AGENT);

        // x_{s+1} prefetch (vmcnt wait lands after the dots)
        float2 xnext = make_float2(0.f, 0.f);
        if (stager && s + 1 < TSTEPS)
            xnext = ((const float2*)(xrow + (s + 1) * FDIM))[sx];

        float A0 = 0.f, A1 = 0.f, A2 = 0.f, A3 = 0.f;

        // early dots: x + own h (12 words, reg weights, LDS broadcast reads)
        #pragma unroll
        for (int wi = 0; wi < 12; ++wi) {
            uint4 xv = Xk[2 * wi];
            DOT4(A0, A1, A2, A3, xv, Wv[wi]);
        }

        // gather AFTER early dots: B1 releases at max(D_early, RTT)
        if (gatherer && s > 0) {
            int it = 0;
            while ((unsigned)(pv >> 32) != (unsigned)s && ++it < (1 << 22))
                pv = __hip_atomic_load(psrc, __ATOMIC_RELAXED,
                                       __HIP_MEMORY_SCOPE_AGENT);
            unsigned pdw = ((unsigned)(pv >> 32) == (unsigned)s) ? (unsigned)pv : 0u;
            ((unsigned*)&xh4[cp][24])[gl] = pdw;           // dw 96+gl
        }
        __syncthreads();                                   // B1

        // late dots: partner h (8 words)
        #pragma unroll
        for (int wi = 12; wi < 20; ++wi) {
            uint4 xv = Xk[2 * wi];
            DOT4(A0, A1, A2, A3, xv, Wv[wi]);
        }

        // reduce kh halves, then gather the 4 gates in-wave
        float z = (A0 + A1) + (A2 + A3);
        z += __shfl_xor(z, 1);
        const float zfv = __shfl_down(z, 2);
        const float zcv = __shfl_down(z, 4);
        const float zov = __shfl_down(z, 6);

        // gate math (all lanes execute; only tid&7==0 lanes hold real values)
        const float zi = z   + bi;
        const float zf = zfv + bf;
        const float zc = zcv + bc;
        const float zo = zov + bo;
        const float ig = 1.0f / (1.0f + __expf(-zi));
        const float fg = 1.0f / (1.0f + __expf(-zf));
        const float gg = 1.0f - 2.0f / (__expf(2.0f * zc) + 1.0f);
        const float og = 1.0f / (1.0f + __expf(-zo));
        cstate = fmaf(fg, cstate, ig * gg);
        const float hn = og * (1.0f - 2.0f / (__expf(2.0f * cstate) + 1.0f));
        const float hno = __shfl_down(hn, 8);              // h_{j+1}

        if ((tid & 7) == 0) {
            if (s == TSTEPS - 1) {
                const float h = hn;
                out[row * HDIM + cg * 128 + j] = (h >= 0.0f) ? h : 0.3f * h;
            } else if ((tid & 15) == 0) {                  // even j
                const unsigned u = pack2(hn, hno);
                const unsigned long long pvw =
                    ((unsigned long long)(unsigned)(s + 1) << 32) |
                    (unsigned long long)u;
                __hip_atomic_store(pubB + (size_t)((s + 1) & 1) * 64 + (j >> 1),
                                   pvw, __ATOMIC_RELAXED,
                                   __HIP_MEMORY_SCOPE_AGENT);
                ((unsigned*)&xh4[ncp][8])[j >> 1] = u;     // own h, dw 32+j/2
            }
        }
        if (stager && s + 1 < TSTEPS)
            ((unsigned*)&xh4[ncp][0])[sx] = pack2(xnext.x, xnext.y);
        __syncthreads();                                   // B3
    }
}

// ---- fallback (needs no ws): round-1 kernel ----
__global__ __launch_bounds__(HDIM) void lstm_fused(
    const float* __restrict__ inputs, const float* __restrict__ wk,
    const float* __restrict__ wr, const float* __restrict__ bias,
    float* __restrict__ out)
{
    const int b = blockIdx.x;
    const int t = threadIdx.x;
    __shared__ float hs[2][HDIM];
    __shared__ float xs[2][FDIM];
    const float* __restrict__ xin = inputs + (size_t)b * TSTEPS * FDIM;
    float c = 0.0f;
    hs[0][t] = 0.0f;
    if (t < FDIM) xs[0][t] = xin[t];
    const float bi = bias[t];
    const float bf = bias[HDIM + t];
    const float bc = bias[2 * HDIM + t];
    const float bo = bias[3 * HDIM + t];
    __syncthreads();
    int p = 0;
    for (int step = 0; step < TSTEPS; ++step) {
        float zi = bi, zf = bf, zc = bc, zo = bo;
        const float* xsp = xs[p];
        const float* hsp = hs[p];
        #pragma unroll 8
        for (int f = 0; f < FDIM; ++f) {
            const float xv = xsp[f];
            const float* Kf = wk + f * G4 + t;
            zi = fmaf(xv, Kf[0], zi);
            zf = fmaf(xv, Kf[HDIM], zf);
            zc = fmaf(xv, Kf[2 * HDIM], zc);
            zo = fmaf(xv, Kf[3 * HDIM], zo);
        }
        #pragma unroll 8
        for (int k = 0; k < HDIM; ++k) {
            const float hv = hsp[k];
            const float* Rk = wr + k * G4 + t;
            zi = fmaf(hv, Rk[0], zi);
            zf = fmaf(hv, Rk[HDIM], zf);
            zc = fmaf(hv, Rk[2 * HDIM], zc);
            zo = fmaf(hv, Rk[3 * HDIM], zo);
        }
        const float ig = 1.0f / (1.0f + __expf(-zi));
        const float fg = 1.0f / (1.0f + __expf(-zf));
        const float gg = 1.0f - 2.0f / (__expf(2.0f * zc) + 1.0f);
        const float og = 1.0f / (1.0f + __expf(-zo));
        c = fmaf(fg, c, ig * gg);
        const float hn = og * (1.0f - 2.0f / (__expf(2.0f * c) + 1.0f));
        float xnext = 0.0f;
        if (t < FDIM && step + 1 < TSTEPS) xnext = xin[(step + 1) * FDIM + t];
        hs[p ^ 1][t] = hn;
        if (t < FDIM) xs[p ^ 1][t] = xnext;
        __syncthreads();
        p ^= 1;
    }
    const float h = hs[p][t];
    out[b * HDIM + t] = (h >= 0.0f) ? h : 0.3f * h;
}

extern "C" void kernel_launch(void* const* d_in, const int* in_sizes, int n_in,
                              void* d_out, int out_size, void* d_ws, size_t ws_size,
                              hipStream_t stream) {
    const float* inputs = (const float*)d_in[0];
    const float* wk     = (const float*)d_in[1];
    const float* wr     = (const float*)d_in[2];
    const float* bias   = (const float*)d_in[3];
    float* out          = (float*)d_out;

    if (ws_size >= (size_t)WS_NEED) {
        unsigned* w4s = (unsigned*)d_ws;
        unsigned long long* ex2 = (unsigned long long*)((char*)d_ws + EX_OFF);
        hipMemsetAsync(ex2, 0xFF, EX_BYTES, stream);   // all tags invalid
        int ndw = W4S_U4 * 4;
        pack_weights2<<<dim3((ndw + 255) / 256), dim3(256), 0, stream>>>(wk, wr, w4s);
        lstm_2way<<<dim3(256), dim3(1024), 0, stream>>>(
            inputs, (const uint4*)w4s, bias, ex2, out);
    } else {
        lstm_fused<<<dim3(BATCH), dim3(HDIM), 0, stream>>>(inputs, wk, wr, bias, out);
    }
}